// Round 3
// baseline (302.086 us; speedup 1.0000x reference)
//
#include <hip/hip_runtime.h>
#include <hip/hip_bf16.h>
#include <stdint.h>

typedef __attribute__((ext_vector_type(8))) short short8;  // 8 bf16 (4 VGPRs)
typedef __attribute__((ext_vector_type(4))) float f32x4;   // 4 fp32 acc

__device__ __forceinline__ uint16_t f2bf(float f) {
    union { float f; uint32_t u; } v; v.f = f;
    uint32_t r = v.u + 0x7FFF + ((v.u >> 16) & 1);  // RNE
    return (uint16_t)(r >> 16);
}
__device__ __forceinline__ float bf2f(uint16_t u) {
    union { uint32_t u; float f; } v; v.u = ((uint32_t)u) << 16;
    return v.f;
}
__device__ __forceinline__ float exp2_raw(float x) {
    float r;
    asm("v_exp_f32 %0, %1" : "=v"(r) : "v"(x));
    return r;
}
__device__ __forceinline__ uint32_t cvt_pk_bf16(float lo, float hi) {
    uint32_t r;
    asm("v_cvt_pk_bf16_f32 %0, %1, %2" : "=v"(r) : "v"(lo), "v"(hi));
    return r;
}

template<int F32>
__device__ __forceinline__ uint4 load8(const void* p, size_t off) {
    if (F32) {
        const float* f = (const float*)p + off;
        float4 f0 = *(const float4*)f;
        float4 f1 = *(const float4*)(f + 4);
        uint4 r;
        r.x = (uint32_t)f2bf(f0.x) | ((uint32_t)f2bf(f0.y) << 16);
        r.y = (uint32_t)f2bf(f0.z) | ((uint32_t)f2bf(f0.w) << 16);
        r.z = (uint32_t)f2bf(f1.x) | ((uint32_t)f2bf(f1.y) << 16);
        r.w = (uint32_t)f2bf(f1.z) | ((uint32_t)f2bf(f1.w) << 16);
        return r;
    } else {
        return *(const uint4*)((const uint16_t*)p + off);
    }
}

// global -> LDS direct DMA, 16 B/lane; LDS dest = wave-uniform base + lane*16.
#define GLDS(gp, lp) __builtin_amdgcn_global_load_lds( \
    (const __attribute__((address_space(1))) void*)(gp), \
    (__attribute__((address_space(3))) void*)(lp), 16, 0, 0)

// ---------------------------------------------------------------------------
// cvt (x + weights + pos) + mask canonicalization fused. Mask is packed
// into a 1024-bit-per-batch bitmask (64 u64 words total) so flash_attn does a
// wave-uniform scalar load per key-tile instead of 4 global v-loads/iter.
// ---------------------------------------------------------------------------
struct CvtSeg { const float* s; uint16_t* d; int n8; };
struct CvtArgs { CvtSeg seg[9]; int nseg; const void* mraw; unsigned long long* mbits; };

__global__ __launch_bounds__(256) void cvt_bf16(CvtArgs a)
{
    if (blockIdx.x == 0) {
        __shared__ int flags[3];
        __shared__ uint8_t mloc[4096];
        const uint32_t* w = (const uint32_t*)a.mraw;
        const uint8_t* b8 = (const uint8_t*)a.mraw;
        const int t = threadIdx.x;
        if (t < 3) flags[t] = 0;
        __syncthreads();
        int fbyte = 0, ff32 = 0, fodd = 0;
        for (int i = t; i < 1024; i += 256) {
            uint32_t v = w[i];
            if (v != 0u && v != 1u && v != 0x3F800000u) fbyte = 1;
            if (v == 0x3F800000u) ff32 = 1;
            if ((i & 1) && v != 0u) fodd = 1;
        }
        if (fbyte) atomicOr(&flags[0], 1);
        if (ff32)  atomicOr(&flags[1], 1);
        if (fodd)  atomicOr(&flags[2], 1);
        __syncthreads();
        int mode;  // 0 = word, 1 = byte, 2 = int64
        if (flags[0]) mode = 1;
        else if (flags[1]) mode = 0;
        else if (!flags[2]) mode = 2;
        else mode = 0;
        for (int k = t; k < 4096; k += 256) {
            int val;
            if (mode == 1)      val = (b8[k] != 0);
            else if (mode == 2) val = (w[2 * k] != 0u);
            else                val = (w[k] != 0u);
            mloc[k] = (uint8_t)val;
        }
        __syncthreads();
        if (t < 64) {
            uint64_t bits = 0;
#pragma unroll
            for (int i = 0; i < 64; ++i)
                bits |= (uint64_t)mloc[t * 64 + i] << i;
            a.mbits[t] = bits;
        }
    }
    const int tid = blockIdx.x * 256 + threadIdx.x;
    const int stride = gridDim.x * 256;
    for (int s = 0; s < a.nseg; ++s) {
        const float* src = a.seg[s].s;
        uint16_t* dst = a.seg[s].d;
        const int n8 = a.seg[s].n8;
        if (src) {
            for (int i = tid; i < n8; i += stride)
                *(uint4*)(dst + (size_t)i * 8) = load8<1>(src, (size_t)i * 8);
        } else {
            const uint4 z = {0u, 0u, 0u, 0u};
            for (int i = tid; i < n8; i += stride)
                *(uint4*)(dst + (size_t)i * 8) = z;
        }
    }
}

// ---------------------------------------------------------------------------
// QKV GEMM, 128x128 tile, BK=64 as TWO 128x32 sub-tiles per operand — exact
// r13 version (best measured). Pure-bf16 glds staging, 32 MFMA per barrier
// pair. NOTE (r9/r10/r14 lesson): never reduce MFMA-per-barrier; never stage
// fp32 rows into LDS (16-way conflict) or via in-loop vector loads (exposed
// vmcnt drain).
// ---------------------------------------------------------------------------
__global__ __launch_bounds__(256) void gemm128_qkv(
    const uint16_t* __restrict__ xq, const uint16_t* __restrict__ xk, const uint16_t* __restrict__ xv,
    const uint16_t* __restrict__ Wq, const uint16_t* __restrict__ Wk, const uint16_t* __restrict__ Wv,
    uint16_t* __restrict__ Qh, uint16_t* __restrict__ Khd, uint16_t* __restrict__ Vt)
{
    __shared__ alignas(16) uint16_t As[2][128 * 32];   // k-halves
    __shared__ alignas(16) uint16_t Bs[2][128 * 32];

    const int z = blockIdx.z;
    const uint16_t* A = (z == 0) ? xq : (z == 1) ? xk : xv;
    const uint16_t* B = (z == 0) ? Wq : (z == 1) ? Wk : Wv;
    uint16_t* C = (z == 0) ? Qh : (z == 1) ? Khd : Vt;
    const int cm = (z == 2) ? 2 : 1;
    const int bm = blockIdx.x, bn = blockIdx.y;
    const int K = 1024;

    const int t = threadIdx.x;
    const int lane = t & 63, wave = t >> 6;
    const int lrow = lane & 15, quad = lane >> 4;
    const int wr = (wave >> 1) * 64, wc = (wave & 1) * 64;
    const int g_row = wave * 16 + (lane >> 2);
    const int g_col = (lane & 3) * 8;

    const f32x4 fz = {0.f, 0.f, 0.f, 0.f};
    f32x4 acc[4][4];
#pragma unroll
    for (int i = 0; i < 4; ++i)
#pragma unroll
        for (int j = 0; j < 4; ++j) acc[i][j] = fz;

    for (int k0 = 0; k0 < K; k0 += 64) {
        __syncthreads();
#pragma unroll
        for (int kh = 0; kh < 2; ++kh) {
            const int kk = k0 + kh * 32;
            GLDS(A + (size_t)(bm * 128 + g_row) * K + kk + g_col,      As[kh] + wave * 512);
            GLDS(A + (size_t)(bm * 128 + g_row + 64) * K + kk + g_col, As[kh] + wave * 512 + 2048);
            GLDS(B + (size_t)(bn * 128 + g_row) * K + kk + g_col,      Bs[kh] + wave * 512);
            GLDS(B + (size_t)(bn * 128 + g_row + 64) * K + kk + g_col, Bs[kh] + wave * 512 + 2048);
        }
        __syncthreads();

#pragma unroll
        for (int kh = 0; kh < 2; ++kh) {
            short8 a[4], b[4];
#pragma unroll
            for (int i = 0; i < 4; ++i)
                a[i] = *(const short8*)(As[kh] + (wr + i * 16 + lrow) * 32 + quad * 8);
#pragma unroll
            for (int j = 0; j < 4; ++j)
                b[j] = *(const short8*)(Bs[kh] + (wc + j * 16 + lrow) * 32 + quad * 8);
#pragma unroll
            for (int i = 0; i < 4; ++i)
#pragma unroll
                for (int j = 0; j < 4; ++j)
                    acc[i][j] = __builtin_amdgcn_mfma_f32_16x16x32_bf16(a[i], b[j], acc[i][j], 0, 0, 0);
        }
    }

    if (cm == 2) {
        __syncthreads();
        uint16_t* scr = As[0] + wave * 1024;
#pragma unroll
        for (int i = 0; i < 4; ++i)
#pragma unroll
            for (int j = 0; j < 4; ++j) {
                uint2 pk;
                pk.x = (uint32_t)f2bf(acc[i][j][0]) | ((uint32_t)f2bf(acc[i][j][1]) << 16);
                pk.y = (uint32_t)f2bf(acc[i][j][2]) | ((uint32_t)f2bf(acc[i][j][3]) << 16);
                *(uint2*)(scr + lrow * 16 + quad * 4) = pk;
                if (lane < 32) {
                    int n = lane >> 1, m8 = (lane & 1) * 8;
                    short8 vv = *(const short8*)(scr + n * 16 + m8);
                    int ng = bn * 128 + wc + j * 16 + n;        // (h,d)
                    int hh = ng >> 6, d = ng & 63;
                    int mg = bm * 128 + wr + i * 16;            // t base
                    int bb = mg >> 10, tl = (mg & 1023) + m8;
                    *(short8*)(C + ((((size_t)bb * 16 + hh) * 64 + d) * 1024 + tl)) = vv;
                }
            }
        return;
    }

#pragma unroll
    for (int i = 0; i < 4; ++i)
#pragma unroll
        for (int j = 0; j < 4; ++j)
#pragma unroll
            for (int r = 0; r < 4; ++r) {
                // verified C/D map: row = quad*4 + reg, col = lane&15
                int m = bm * 128 + wr + i * 16 + quad * 4 + r;
                int n = bn * 128 + wc + j * 16 + lrow;
                int bb = m >> 10, tt = m & 1023, hh = n >> 6, d = n & 63;
                C[(((size_t)bb * 16 + hh) * 1024 + tt) * 64 + d] = f2bf(acc[i][j][r]);
            }
}

// ---------------------------------------------------------------------------
// Output projection, 64x128 tiles (512 blocks = 2/CU), BK=64 — exact r13
// version. 16 MFMA/iter. LDS 24KB.
// ---------------------------------------------------------------------------
__global__ __launch_bounds__(256) void gemm_out(
    const uint16_t* __restrict__ A, const uint16_t* __restrict__ B,
    float* __restrict__ C, int M, int N, int K)
{
    __shared__ alignas(16) uint16_t As[2][64 * 32];
    __shared__ alignas(16) uint16_t Bs[2][128 * 32];

    const int t = threadIdx.x;
    const int lane = t & 63, wave = t >> 6;
    const int lrow = lane & 15, quad = lane >> 4;
    const int wr = (wave >> 1) * 32, wc = (wave & 1) * 64;
    const int g_row = wave * 16 + (lane >> 2);
    const int g_col = (lane & 3) * 8;
    const int bm = blockIdx.x, bn = blockIdx.y;

    const f32x4 fz = {0.f, 0.f, 0.f, 0.f};
    f32x4 acc[2][4];
#pragma unroll
    for (int i = 0; i < 2; ++i)
#pragma unroll
        for (int j = 0; j < 4; ++j) acc[i][j] = fz;

    for (int k0 = 0; k0 < K; k0 += 64) {
        __syncthreads();
#pragma unroll
        for (int kh = 0; kh < 2; ++kh) {
            const int kk = k0 + kh * 32;
            GLDS(A + (size_t)(bm * 64 + g_row) * K + kk + g_col,       As[kh] + wave * 512);
            GLDS(B + (size_t)(bn * 128 + g_row) * K + kk + g_col,      Bs[kh] + wave * 512);
            GLDS(B + (size_t)(bn * 128 + g_row + 64) * K + kk + g_col, Bs[kh] + wave * 512 + 2048);
        }
        __syncthreads();

#pragma unroll
        for (int kh = 0; kh < 2; ++kh) {
            short8 a[2], b[4];
#pragma unroll
            for (int i = 0; i < 2; ++i)
                a[i] = *(const short8*)(As[kh] + (wr + i * 16 + lrow) * 32 + quad * 8);
#pragma unroll
            for (int j = 0; j < 4; ++j)
                b[j] = *(const short8*)(Bs[kh] + (wc + j * 16 + lrow) * 32 + quad * 8);
#pragma unroll
            for (int i = 0; i < 2; ++i)
#pragma unroll
                for (int j = 0; j < 4; ++j)
                    acc[i][j] = __builtin_amdgcn_mfma_f32_16x16x32_bf16(a[i], b[j], acc[i][j], 0, 0, 0);
        }
    }

#pragma unroll
    for (int i = 0; i < 2; ++i)
#pragma unroll
        for (int j = 0; j < 4; ++j)
#pragma unroll
            for (int r = 0; r < 4; ++r) {
                int m = bm * 64 + wr + i * 16 + quad * 4 + r;
                int n = bn * 128 + wc + j * 16 + lrow;
                C[(size_t)m * N + n] = acc[i][j][r];
            }
}

// ---------------------------------------------------------------------------
// Flash attention v10 — barrier-free, LDS-staging-free (m169 play).
// K/V per (b,h) = 256KB, shared by 16 blocks pinned to one XCD by the blk
// swizzle -> K/V is L2-resident; per row each tile reads exactly one 128B
// line; the 4 waves of a block read the same 8KB tiles -> L1 serves 3/4.
// So Ks/Vs/GLDS/double-buffer and ALL __syncthreads are deleted:
//  * K as register b-frags, software-pipelined one tile ahead (ka/kn swap
//    via 2-body unroll -> all static indexing, rule-20 safe).
//  * V issued at tile top, consumed after softmax (~200cy cover).
//  * Qpos slab + Pl are WAVE-PRIVATE (ql = wave*16+quad*4+r; Pl[wave][..])
//    -> no inter-wave ordering needed anywhere.
//  * Addressing: per-lane-constant voffset + wave-uniform tile base.
// LDS: Qpos 35.5K + Pl 9K = 44.7K -> 3 blocks/CU (was 2 at 77.8K).
// Kept from v9 (proven): mask bitmask, exp2+CS prescale, cvt_pk packing,
// Qpos width 277, setprio around MFMA clusters.
// ---------------------------------------------------------------------------
#define FA_BODY(TI, KC, KN)                                                         \
{                                                                                   \
    const int kb = (TI) * 64;                                                       \
    short8 vv[8];                                                                   \
    _Pragma("unroll")                                                               \
    for (int dt = 0; dt < 4; ++dt) {                                                \
        vv[dt * 2 + 0] = *(const short8*)(Vrow + (size_t)dt * 16384 + kb);          \
        vv[dt * 2 + 1] = *(const short8*)(Vrow + (size_t)dt * 16384 + kb + 32);     \
    }                                                                               \
    const int kbn = (((TI) + 1) & 15) * 64;                                         \
    _Pragma("unroll")                                                               \
    for (int j = 0; j < 4; ++j) {                                                   \
        KN[j * 2 + 0] = *(const short8*)(Krow + (size_t)(kbn + j * 16) * 64);       \
        KN[j * 2 + 1] = *(const short8*)(Krow + (size_t)(kbn + j * 16) * 64 + 32);  \
    }                                                                               \
    const unsigned long long mb = mk64[(TI)];                                       \
    f32x4 s[4];                                                                     \
    __builtin_amdgcn_s_setprio(1);                                                  \
    _Pragma("unroll")                                                               \
    for (int j = 0; j < 4; ++j) {                                                   \
        s[j] = __builtin_amdgcn_mfma_f32_16x16x32_bf16(aq0, KC[j * 2 + 0], fz, 0, 0, 0); \
        s[j] = __builtin_amdgcn_mfma_f32_16x16x32_bf16(aq1, KC[j * 2 + 1], s[j], 0, 0, 0); \
    }                                                                               \
    __builtin_amdgcn_s_setprio(0);                                                  \
    const int diff = kb - qb;                                                       \
    if (diff <= -192 || diff >= 144) {                                              \
        const bool low = (diff <= -192);                                            \
        _Pragma("unroll")                                                           \
        for (int j = 0; j < 4; ++j) {                                               \
            const uint32_t mj = ((uint32_t)(mb >> (j * 16)) >> lrow) & 1u;          \
            float e[4];                                                             \
            _Pragma("unroll")                                                       \
            for (int r = 0; r < 4; ++r) {                                           \
                float pc = low ? pcl[r] : pch[r];                                   \
                float ev = exp2_raw(__builtin_fmaf(s[j][r], CS, pc));               \
                ev = mj ? 0.f : ev;                                                 \
                lsum[r] += ev;                                                      \
                e[r] = ev;                                                          \
            }                                                                       \
            const uint32_t p01 = cvt_pk_bf16(e[0], e[1]);                           \
            const uint32_t p23 = cvt_pk_bf16(e[2], e[3]);                           \
            const int col = j * 16 + lrow;                                          \
            const int rw = quad * 4;                                                \
            Pl[wave][rw + 0][col] = (uint16_t)p01;                                  \
            Pl[wave][rw + 1][col] = (uint16_t)(p01 >> 16);                          \
            Pl[wave][rw + 2][col] = (uint16_t)p23;                                  \
            Pl[wave][rw + 3][col] = (uint16_t)(p23 >> 16);                          \
        }                                                                           \
    } else {                                                                        \
        _Pragma("unroll")                                                           \
        for (int j = 0; j < 4; ++j) {                                               \
            const int key = kb + j * 16 + lrow;                                     \
            const uint32_t mj = ((uint32_t)(mb >> (j * 16)) >> lrow) & 1u;          \
            float e[4];                                                             \
            _Pragma("unroll")                                                       \
            for (int r = 0; r < 4; ++r) {                                           \
                int q = qb + quad * 4 + r;                                          \
                int ql = q & 63;                                                    \
                int rel = min(max(key - q, -128), 128) + 128;                       \
                float p = bf2f(Qpos_l[ql][rel]);                                    \
                float ev = exp2_raw(__builtin_fmaf(s[j][r], CS, p));                \
                ev = mj ? 0.f : ev;                                                 \
                lsum[r] += ev;                                                      \
                e[r] = ev;                                                          \
            }                                                                       \
            const uint32_t p01 = cvt_pk_bf16(e[0], e[1]);                           \
            const uint32_t p23 = cvt_pk_bf16(e[2], e[3]);                           \
            const int col = j * 16 + lrow;                                          \
            const int rw = quad * 4;                                                \
            Pl[wave][rw + 0][col] = (uint16_t)p01;                                  \
            Pl[wave][rw + 1][col] = (uint16_t)(p01 >> 16);                          \
            Pl[wave][rw + 2][col] = (uint16_t)p23;                                  \
            Pl[wave][rw + 3][col] = (uint16_t)(p23 >> 16);                          \
        }                                                                           \
    }                                                                               \
    short8 ap0 = *(const short8*)(&Pl[wave][lrow][quad * 8]);                       \
    short8 ap1 = *(const short8*)(&Pl[wave][lrow][32 + quad * 8]);                  \
    __builtin_amdgcn_s_setprio(1);                                                  \
    _Pragma("unroll")                                                               \
    for (int dt = 0; dt < 4; ++dt) {                                                \
        o[dt] = __builtin_amdgcn_mfma_f32_16x16x32_bf16(ap0, vv[dt * 2 + 0], o[dt], 0, 0, 0); \
        o[dt] = __builtin_amdgcn_mfma_f32_16x16x32_bf16(ap1, vv[dt * 2 + 1], o[dt], 0, 0, 0); \
    }                                                                               \
    __builtin_amdgcn_s_setprio(0);                                                  \
}

__global__ __launch_bounds__(256) void flash_attn(
    const uint16_t* __restrict__ Qh, const uint16_t* __restrict__ Kh,
    const uint16_t* __restrict__ Vt, const uint16_t* __restrict__ pos,
    const unsigned long long* __restrict__ mask64, uint16_t* __restrict__ comb)
{
    const int blk = blockIdx.x;     // 0..1023
    const int jj = blk >> 3;        // 0..127
    const int bh = (blk & 7) * 8 + (jj >> 4);   // XCD-locality swizzle
    const int qt = jj & 15;
    const int b = bh >> 4;
    const int h = bh & 15;
    const int t = threadIdx.x;
    const int lane = t & 63;
    const int wave = t >> 6;
    const int lrow = lane & 15;
    const int quad = lane >> 4;
    const int qb = qt * 64 + wave * 16;

    __shared__ alignas(16) uint16_t Qpos_l[64][277];   // 35456 B, wave-private rows
    __shared__ alignas(16) uint16_t Pl[4][16][72];     // 9216 B, wave-private

    const uint16_t* Kp = Kh + (size_t)bh * 65536;
    const uint16_t* Vp = Vt + (size_t)bh * 65536;
    const unsigned long long* mk64 = mask64 + b * 16;

    const float CS = 0.18033688011f;   // 0.125 * log2(e)

    // per-lane row bases: K[key][d] rows, V[d][t] rows
    const uint16_t* Krow = Kp + (size_t)lrow * 64 + quad * 8;
    const uint16_t* Vrow = Vp + (size_t)lrow * 1024 + quad * 8;

    const uint16_t* Qp = Qh + ((size_t)bh * 1024 + qb) * 64;
    short8 aq0 = *(const short8*)(Qp + (size_t)lrow * 64 + quad * 8);
    short8 aq1 = *(const short8*)(Qp + (size_t)lrow * 64 + 32 + quad * 8);

    const f32x4 fz = {0.f, 0.f, 0.f, 0.f};

    // issue tile-0 K loads first: L2 latency hides under the slab prologue
    short8 ka[8], kn[8];
#pragma unroll
    for (int j = 0; j < 4; ++j) {
        ka[j * 2 + 0] = *(const short8*)(Krow + (size_t)(j * 16) * 64);
        ka[j * 2 + 1] = *(const short8*)(Krow + (size_t)(j * 16) * 64 + 32);
    }

    // ---- prologue: 16x272 pos-logit slab (pre-scaled by CS), B-frags from
    // global (L2-hot). cvt_pk packs pairs; each wave writes only its 16 rows.
#pragma unroll 4
    for (int nt = 0; nt < 17; ++nt) {
        short8 pb0 = *(const short8*)(pos + (size_t)(nt * 16 + lrow) * 64 + quad * 8);
        short8 pb1 = *(const short8*)(pos + (size_t)(nt * 16 + lrow) * 64 + 32 + quad * 8);
        f32x4 c = __builtin_amdgcn_mfma_f32_16x16x32_bf16(aq0, pb0, fz, 0, 0, 0);
        c = __builtin_amdgcn_mfma_f32_16x16x32_bf16(aq1, pb1, c, 0, 0, 0);
        const uint32_t p01 = cvt_pk_bf16(c[0] * CS, c[1] * CS);
        const uint32_t p23 = cvt_pk_bf16(c[2] * CS, c[3] * CS);
        const int row = wave * 16 + quad * 4;
        const int col = nt * 16 + lrow;
        Qpos_l[row + 0][col] = (uint16_t)p01;
        Qpos_l[row + 1][col] = (uint16_t)(p01 >> 16);
        Qpos_l[row + 2][col] = (uint16_t)p23;
        Qpos_l[row + 3][col] = (uint16_t)(p23 >> 16);
    }

    float pcl[4], pch[4];
#pragma unroll
    for (int r = 0; r < 4; ++r) {
        int ql = wave * 16 + quad * 4 + r;
        pcl[r] = bf2f(Qpos_l[ql][0]);      // already * CS
        pch[r] = bf2f(Qpos_l[ql][256]);
    }

    f32x4 o[4] = {fz, fz, fz, fz};
    float lsum[4] = {0.f, 0.f, 0.f, 0.f};

    for (int t2 = 0; t2 < 16; t2 += 2) {
        FA_BODY(t2, ka, kn)
        FA_BODY(t2 + 1, kn, ka)
    }

#pragma unroll
    for (int off = 1; off < 16; off <<= 1)
#pragma unroll
        for (int r = 0; r < 4; ++r)
            lsum[r] += __shfl_xor(lsum[r], off);

    float inv[4];
#pragma unroll
    for (int r = 0; r < 4; ++r) inv[r] = 1.0f / lsum[r];

#pragma unroll
    for (int dt = 0; dt < 4; ++dt)
#pragma unroll
        for (int r = 0; r < 4; ++r) {
            size_t row = (size_t)b * 1024 + qb + quad * 4 + r;
            size_t col = (size_t)h * 64 + dt * 16 + lrow;
            comb[row * 1024 + col] = f2bf(o[dt][r] * inv[r]);
        }
}

// ---------------------------------------------------------------------------
// ws layout (~56.1 MB; ws_size >= ~72 MB evidenced rounds 0-3):
// Qh 8 | Khd 8 | Vt 8 | xqb 8 (comb reuse) | xkb 8 | xvb 8 | W*4 8 | posb | mbits
// ---------------------------------------------------------------------------
extern "C" void kernel_launch(void* const* d_in, const int* in_sizes, int n_in,
                              void* d_out, int out_size, void* d_ws, size_t ws_size,
                              hipStream_t stream)
{
    const float* x_q = (const float*)d_in[0];
    const float* x_k = (const float*)d_in[1];
    const float* x_v = (const float*)d_in[2];
    const void*  msk = d_in[3];
    const float* Wq  = (const float*)d_in[4];
    const float* Wk  = (const float*)d_in[5];
    const float* Wv  = (const float*)d_in[6];
    const float* Wo  = (const float*)d_in[7];
    const float* pos = (const float*)d_in[8];

    char* ws = (char*)d_ws;
    const size_t MB = 1u << 20;
    uint16_t* Qh   = (uint16_t*)(ws);
    uint16_t* Khd  = (uint16_t*)(ws + 8 * MB);
    uint16_t* Vt   = (uint16_t*)(ws + 16 * MB);
    uint16_t* xqb  = (uint16_t*)(ws + 24 * MB);
    uint16_t* xkb  = (uint16_t*)(ws + 32 * MB);
    uint16_t* xvb  = (uint16_t*)(ws + 40 * MB);
    uint16_t* Wqb  = (uint16_t*)(ws + 48 * MB);
    uint16_t* Wkb  = (uint16_t*)(ws + 50 * MB);
    uint16_t* Wvb  = (uint16_t*)(ws + 52 * MB);
    uint16_t* Wob  = (uint16_t*)(ws + 54 * MB);
    uint16_t* posb = (uint16_t*)(ws + 56 * MB);       // 272x64 bf16, rows 257+ zero
    unsigned long long* mbits = (unsigned long long*)(ws + 56 * MB + 65536);
    uint16_t* comb = xqb;  // xqb dead after projections; flash runs after them

    CvtArgs ca{};
    int ns = 0;
    ca.seg[ns++] = {x_q, xqb, 524288};
    ca.seg[ns++] = {x_k, xkb, 524288};
    ca.seg[ns++] = {x_v, xvb, 524288};
    ca.seg[ns++] = {Wq, Wqb, 131072};
    ca.seg[ns++] = {Wk, Wkb, 131072};
    ca.seg[ns++] = {Wv, Wvb, 131072};
    ca.seg[ns++] = {Wo, Wob, 131072};
    ca.seg[ns++] = {pos, posb, 2056};              // 257*64/8
    ca.seg[ns++] = {nullptr, posb + 16448, 120};   // zero rows 257..271
    ca.nseg = ns;
    ca.mraw = msk;
    ca.mbits = mbits;
    cvt_bf16<<<dim3(1024), dim3(256), 0, stream>>>(ca);

    // Fused Q/K/V projections, BK=64 two-half staging: 32x8x3 = 768 blocks
    gemm128_qkv<<<dim3(32, 8, 3), dim3(256), 0, stream>>>(
        xqb, xkb, xvb, Wqb, Wkb, Wvb, Qh, Khd, Vt);

    flash_attn<<<dim3(1024), dim3(256), 0, stream>>>(Qh, Khd, Vt, posb, mbits, comb);

    // Output projection: comb(bf16) @ Wo_b^T -> fp32 d_out (64x128, BK=64)
    gemm_out<<<dim3(64, 8), dim3(256), 0, stream>>>(
        comb, Wob, (float*)d_out, 4096, 1024, 1024);
}

// Round 4
// 237.282 us; speedup vs baseline: 1.2731x; 1.2731x over previous
//
#include <hip/hip_runtime.h>
#include <hip/hip_bf16.h>
#include <stdint.h>

typedef __attribute__((ext_vector_type(8))) short short8;  // 8 bf16 (4 VGPRs)
typedef __attribute__((ext_vector_type(4))) float f32x4;   // 4 fp32 acc

__device__ __forceinline__ uint16_t f2bf(float f) {
    union { float f; uint32_t u; } v; v.f = f;
    uint32_t r = v.u + 0x7FFF + ((v.u >> 16) & 1);  // RNE
    return (uint16_t)(r >> 16);
}
__device__ __forceinline__ float bf2f(uint16_t u) {
    union { uint32_t u; float f; } v; v.u = ((uint32_t)u) << 16;
    return v.f;
}
__device__ __forceinline__ float exp2_raw(float x) {
    float r;
    asm("v_exp_f32 %0, %1" : "=v"(r) : "v"(x));
    return r;
}
__device__ __forceinline__ uint32_t cvt_pk_bf16(float lo, float hi) {
    uint32_t r;
    asm("v_cvt_pk_bf16_f32 %0, %1, %2" : "=v"(r) : "v"(lo), "v"(hi));
    return r;
}

template<int F32>
__device__ __forceinline__ uint4 load8(const void* p, size_t off) {
    if (F32) {
        const float* f = (const float*)p + off;
        float4 f0 = *(const float4*)f;
        float4 f1 = *(const float4*)(f + 4);
        uint4 r;
        r.x = (uint32_t)f2bf(f0.x) | ((uint32_t)f2bf(f0.y) << 16);
        r.y = (uint32_t)f2bf(f0.z) | ((uint32_t)f2bf(f0.w) << 16);
        r.z = (uint32_t)f2bf(f1.x) | ((uint32_t)f2bf(f1.y) << 16);
        r.w = (uint32_t)f2bf(f1.z) | ((uint32_t)f2bf(f1.w) << 16);
        return r;
    } else {
        return *(const uint4*)((const uint16_t*)p + off);
    }
}

// global -> LDS direct DMA, 16 B/lane; LDS dest = wave-uniform base + lane*16.
#define GLDS(gp, lp) __builtin_amdgcn_global_load_lds( \
    (const __attribute__((address_space(1))) void*)(gp), \
    (__attribute__((address_space(3))) void*)(lp), 16, 0, 0)

// ---------------------------------------------------------------------------
// cvt (x + weights + pos) + mask canonicalization fused. Mask products:
//  * mbits: 1024-bit-per-batch bitmask (used by gemm128_qkv V-epilogue)
//  * mvals: bf16 {1.0 unmasked, 0.0 masked} per (b,k) — flash_attn's
//    denominator B-fragment (lsum via MFMA instead of 64 VALU adds/iter).
// ---------------------------------------------------------------------------
struct CvtSeg { const float* s; uint16_t* d; int n8; };
struct CvtArgs {
    CvtSeg seg[9]; int nseg;
    const void* mraw; unsigned long long* mbits; uint16_t* mvals;
};

__global__ __launch_bounds__(256) void cvt_bf16(CvtArgs a)
{
    if (blockIdx.x == 0) {
        __shared__ int flags[3];
        __shared__ uint8_t mloc[4096];
        const uint32_t* w = (const uint32_t*)a.mraw;
        const uint8_t* b8 = (const uint8_t*)a.mraw;
        const int t = threadIdx.x;
        if (t < 3) flags[t] = 0;
        __syncthreads();
        int fbyte = 0, ff32 = 0, fodd = 0;
        for (int i = t; i < 1024; i += 256) {
            uint32_t v = w[i];
            if (v != 0u && v != 1u && v != 0x3F800000u) fbyte = 1;
            if (v == 0x3F800000u) ff32 = 1;
            if ((i & 1) && v != 0u) fodd = 1;
        }
        if (fbyte) atomicOr(&flags[0], 1);
        if (ff32)  atomicOr(&flags[1], 1);
        if (fodd)  atomicOr(&flags[2], 1);
        __syncthreads();
        int mode;  // 0 = word, 1 = byte, 2 = int64
        if (flags[0]) mode = 1;
        else if (flags[1]) mode = 0;
        else if (!flags[2]) mode = 2;
        else mode = 0;
        for (int k = t; k < 4096; k += 256) {
            int val;
            if (mode == 1)      val = (b8[k] != 0);
            else if (mode == 2) val = (w[2 * k] != 0u);
            else                val = (w[k] != 0u);
            mloc[k] = (uint8_t)val;
        }
        __syncthreads();
        for (int k = t; k < 4096; k += 256)
            a.mvals[k] = mloc[k] ? (uint16_t)0 : (uint16_t)0x3F80;
        if (t < 64) {
            uint64_t bits = 0;
#pragma unroll
            for (int i = 0; i < 64; ++i)
                bits |= (uint64_t)mloc[t * 64 + i] << i;
            a.mbits[t] = bits;
        }
    }
    const int tid = blockIdx.x * 256 + threadIdx.x;
    const int stride = gridDim.x * 256;
    for (int s = 0; s < a.nseg; ++s) {
        const float* src = a.seg[s].s;
        uint16_t* dst = a.seg[s].d;
        const int n8 = a.seg[s].n8;
        if (src) {
            for (int i = tid; i < n8; i += stride)
                *(uint4*)(dst + (size_t)i * 8) = load8<1>(src, (size_t)i * 8);
        } else {
            const uint4 z = {0u, 0u, 0u, 0u};
            for (int i = tid; i < n8; i += stride)
                *(uint4*)(dst + (size_t)i * 8) = z;
        }
    }
}

// ---------------------------------------------------------------------------
// QKV GEMM, 128x128 tile, BK=64 as TWO 128x32 sub-tiles per operand — exact
// r13 version (best measured). Pure-bf16 glds staging, 32 MFMA per barrier
// pair. NOTE (r9/r10/r14 lesson): never reduce MFMA-per-barrier; never stage
// fp32 rows into LDS (16-way conflict) or via in-loop vector loads (exposed
// vmcnt drain).
// NEW (r4): z==2 (V) epilogue zeroes masked key columns, so flash_attn's
// PV ignores masked keys with NO per-element mask work in the softmax loop.
// ---------------------------------------------------------------------------
__global__ __launch_bounds__(256) void gemm128_qkv(
    const uint16_t* __restrict__ xq, const uint16_t* __restrict__ xk, const uint16_t* __restrict__ xv,
    const uint16_t* __restrict__ Wq, const uint16_t* __restrict__ Wk, const uint16_t* __restrict__ Wv,
    uint16_t* __restrict__ Qh, uint16_t* __restrict__ Khd, uint16_t* __restrict__ Vt,
    const unsigned long long* __restrict__ mbits)
{
    __shared__ alignas(16) uint16_t As[2][128 * 32];   // k-halves
    __shared__ alignas(16) uint16_t Bs[2][128 * 32];

    const int z = blockIdx.z;
    const uint16_t* A = (z == 0) ? xq : (z == 1) ? xk : xv;
    const uint16_t* B = (z == 0) ? Wq : (z == 1) ? Wk : Wv;
    uint16_t* C = (z == 0) ? Qh : (z == 1) ? Khd : Vt;
    const int cm = (z == 2) ? 2 : 1;
    const int bm = blockIdx.x, bn = blockIdx.y;
    const int K = 1024;

    const int t = threadIdx.x;
    const int lane = t & 63, wave = t >> 6;
    const int lrow = lane & 15, quad = lane >> 4;
    const int wr = (wave >> 1) * 64, wc = (wave & 1) * 64;
    const int g_row = wave * 16 + (lane >> 2);
    const int g_col = (lane & 3) * 8;

    const f32x4 fz = {0.f, 0.f, 0.f, 0.f};
    f32x4 acc[4][4];
#pragma unroll
    for (int i = 0; i < 4; ++i)
#pragma unroll
        for (int j = 0; j < 4; ++j) acc[i][j] = fz;

    for (int k0 = 0; k0 < K; k0 += 64) {
        __syncthreads();
#pragma unroll
        for (int kh = 0; kh < 2; ++kh) {
            const int kk = k0 + kh * 32;
            GLDS(A + (size_t)(bm * 128 + g_row) * K + kk + g_col,      As[kh] + wave * 512);
            GLDS(A + (size_t)(bm * 128 + g_row + 64) * K + kk + g_col, As[kh] + wave * 512 + 2048);
            GLDS(B + (size_t)(bn * 128 + g_row) * K + kk + g_col,      Bs[kh] + wave * 512);
            GLDS(B + (size_t)(bn * 128 + g_row + 64) * K + kk + g_col, Bs[kh] + wave * 512 + 2048);
        }
        __syncthreads();

#pragma unroll
        for (int kh = 0; kh < 2; ++kh) {
            short8 a[4], b[4];
#pragma unroll
            for (int i = 0; i < 4; ++i)
                a[i] = *(const short8*)(As[kh] + (wr + i * 16 + lrow) * 32 + quad * 8);
#pragma unroll
            for (int j = 0; j < 4; ++j)
                b[j] = *(const short8*)(Bs[kh] + (wc + j * 16 + lrow) * 32 + quad * 8);
#pragma unroll
            for (int i = 0; i < 4; ++i)
#pragma unroll
                for (int j = 0; j < 4; ++j)
                    acc[i][j] = __builtin_amdgcn_mfma_f32_16x16x32_bf16(a[i], b[j], acc[i][j], 0, 0, 0);
        }
    }

    if (cm == 2) {
        __syncthreads();
        uint16_t* scr = As[0] + wave * 1024;
#pragma unroll
        for (int i = 0; i < 4; ++i)
#pragma unroll
            for (int j = 0; j < 4; ++j) {
                uint2 pk;
                pk.x = (uint32_t)f2bf(acc[i][j][0]) | ((uint32_t)f2bf(acc[i][j][1]) << 16);
                pk.y = (uint32_t)f2bf(acc[i][j][2]) | ((uint32_t)f2bf(acc[i][j][3]) << 16);
                *(uint2*)(scr + lrow * 16 + quad * 4) = pk;
                if (lane < 32) {
                    int n = lane >> 1, m8 = (lane & 1) * 8;
                    short8 vv = *(const short8*)(scr + n * 16 + m8);
                    int ng = bn * 128 + wc + j * 16 + n;        // (h,d)
                    int hh = ng >> 6, d = ng & 63;
                    int mg = bm * 128 + wr + i * 16;            // t base
                    int bb = mg >> 10, tl = (mg & 1023) + m8;
                    // zero masked key columns (tl is 8-aligned; never straddles u64)
                    uint32_t eb = (uint32_t)(mbits[(size_t)bb * 16 + (tl >> 6)] >> (tl & 63)) & 0xFFu;
                    if (eb) {
                        union { short8 s; uint32_t u[4]; } uw;
                        uw.s = vv;
#pragma unroll
                        for (int c = 0; c < 4; ++c) {
                            uint32_t km = (((eb >> (2 * c)) & 1) ? 0u : 0x0000FFFFu)
                                        | (((eb >> (2 * c + 1)) & 1) ? 0u : 0xFFFF0000u);
                            uw.u[c] &= km;
                        }
                        vv = uw.s;
                    }
                    *(short8*)(C + ((((size_t)bb * 16 + hh) * 64 + d) * 1024 + tl)) = vv;
                }
            }
        return;
    }

#pragma unroll
    for (int i = 0; i < 4; ++i)
#pragma unroll
        for (int j = 0; j < 4; ++j)
#pragma unroll
            for (int r = 0; r < 4; ++r) {
                // verified C/D map: row = quad*4 + reg, col = lane&15
                int m = bm * 128 + wr + i * 16 + quad * 4 + r;
                int n = bn * 128 + wc + j * 16 + lrow;
                int bb = m >> 10, tt = m & 1023, hh = n >> 6, d = n & 63;
                C[(((size_t)bb * 16 + hh) * 1024 + tt) * 64 + d] = f2bf(acc[i][j][r]);
            }
}

// ---------------------------------------------------------------------------
// Output projection, 64x128 tiles (512 blocks = 2/CU), BK=64 — exact r13
// version. 16 MFMA/iter. LDS 24KB.
// ---------------------------------------------------------------------------
__global__ __launch_bounds__(256) void gemm_out(
    const uint16_t* __restrict__ A, const uint16_t* __restrict__ B,
    float* __restrict__ C, int M, int N, int K)
{
    __shared__ alignas(16) uint16_t As[2][64 * 32];
    __shared__ alignas(16) uint16_t Bs[2][128 * 32];

    const int t = threadIdx.x;
    const int lane = t & 63, wave = t >> 6;
    const int lrow = lane & 15, quad = lane >> 4;
    const int wr = (wave >> 1) * 32, wc = (wave & 1) * 64;
    const int g_row = wave * 16 + (lane >> 2);
    const int g_col = (lane & 3) * 8;
    const int bm = blockIdx.x, bn = blockIdx.y;

    const f32x4 fz = {0.f, 0.f, 0.f, 0.f};
    f32x4 acc[2][4];
#pragma unroll
    for (int i = 0; i < 2; ++i)
#pragma unroll
        for (int j = 0; j < 4; ++j) acc[i][j] = fz;

    for (int k0 = 0; k0 < K; k0 += 64) {
        __syncthreads();
#pragma unroll
        for (int kh = 0; kh < 2; ++kh) {
            const int kk = k0 + kh * 32;
            GLDS(A + (size_t)(bm * 64 + g_row) * K + kk + g_col,       As[kh] + wave * 512);
            GLDS(B + (size_t)(bn * 128 + g_row) * K + kk + g_col,      Bs[kh] + wave * 512);
            GLDS(B + (size_t)(bn * 128 + g_row + 64) * K + kk + g_col, Bs[kh] + wave * 512 + 2048);
        }
        __syncthreads();

#pragma unroll
        for (int kh = 0; kh < 2; ++kh) {
            short8 a[2], b[4];
#pragma unroll
            for (int i = 0; i < 2; ++i)
                a[i] = *(const short8*)(As[kh] + (wr + i * 16 + lrow) * 32 + quad * 8);
#pragma unroll
            for (int j = 0; j < 4; ++j)
                b[j] = *(const short8*)(Bs[kh] + (wc + j * 16 + lrow) * 32 + quad * 8);
#pragma unroll
            for (int i = 0; i < 2; ++i)
#pragma unroll
                for (int j = 0; j < 4; ++j)
                    acc[i][j] = __builtin_amdgcn_mfma_f32_16x16x32_bf16(a[i], b[j], acc[i][j], 0, 0, 0);
        }
    }

#pragma unroll
    for (int i = 0; i < 2; ++i)
#pragma unroll
        for (int j = 0; j < 4; ++j)
#pragma unroll
            for (int r = 0; r < 4; ++r) {
                int m = bm * 64 + wr + i * 16 + quad * 4 + r;
                int n = bn * 128 + wc + j * 16 + lrow;
                C[(size_t)m * N + n] = acc[i][j][r];
            }
}

// ---------------------------------------------------------------------------
// Flash attention v11 — v9 structure (proven 65.9us) + MFMA-offloaded
// bookkeeping:
//  * V columns for masked keys are pre-zeroed (gemm epilogue) -> the softmax
//    loop has NO mask handling at all (was 64 cndmask + bit extract /iter).
//  * denominator lsum computed as lacc = P_tile x maskv via 2 extra MFMA/iter
//    (B-frag = bf16 0/1 mask, broadcast ds_read from 2KB LDS row) — removes
//    64 VALU adds/iter AND the final 16-wide shfl_xor reduction (every lane's
//    lacc[r] is already the full row sum since all B columns are identical).
// Everything else identical to v9: GLDS-staged double-buffered K/V, mask-free
// exp2(fma) softmax, cvt_pk packing, Qpos width 277, K/V chunk swizzle,
// setprio around MFMA clusters.
// LDS: Ks 16K + Vs 16K + Qpos_l 35.5K + Pl 9K + maskl 2K = 79.5KB -> 2/CU.
// ---------------------------------------------------------------------------
__global__ __launch_bounds__(256) void flash_attn(
    const uint16_t* __restrict__ Qh, const uint16_t* __restrict__ Kh,
    const uint16_t* __restrict__ Vt, const uint16_t* __restrict__ pos,
    const uint16_t* __restrict__ maskv, uint16_t* __restrict__ comb)
{
    const int blk = blockIdx.x;     // 0..1023
    const int jj = blk >> 3;        // 0..127
    const int bh = (blk & 7) * 8 + (jj >> 4);   // XCD-locality swizzle
    const int qt = jj & 15;
    const int b = bh >> 4;
    const int h = bh & 15;
    const int t = threadIdx.x;
    const int lane = t & 63;
    const int wave = t >> 6;
    const int lrow = lane & 15;
    const int quad = lane >> 4;
    const int qb = qt * 64 + wave * 16;

    __shared__ alignas(16) uint16_t Ks[2][4096];       // 2 x 8 KB
    __shared__ alignas(16) uint16_t Vs[2][4096];       // 2 x 8 KB
    __shared__ alignas(16) uint16_t Qpos_l[64][277];   // 35456 B, W=277: bank-clean
    __shared__ alignas(16) uint16_t Pl[4][16][72];     // 9216 B
    __shared__ alignas(16) uint16_t maskl[1024];       // 2 KB bf16 0/1 per key

    const uint16_t* Kp = Kh + (size_t)bh * 65536;
    const uint16_t* Vp = Vt + (size_t)bh * 65536;

    const int sg_r = lane >> 2;
    // pre-swizzled global source chunk: LDS stays linear for GLDS, data lands
    // at chunk position c with content c^((row>>1)&3). Read side mirrors it.
    const int sg_c = ((lane & 3) ^ ((sg_r >> 1) & 3)) * 8;
    const int hw = wave >> 1;
    const int gw = (wave & 1) * 2;
    const int rdc = (quad ^ ((lrow >> 1) & 3)) * 8;    // swizzled read chunk

    const float CS = 0.18033688011f;   // 0.125 * log2(e)

    // issue tile-0 staging first: latency hides under the pos-slab prologue
#pragma unroll
    for (int gg = 0; gg < 2; ++gg) {
        int g = gw + gg;
        GLDS(Kp + (size_t)(g * 16 + sg_r) * 64 + hw * 32 + sg_c, &Ks[0][hw * 2048 + g * 512]);
        GLDS(Vp + (size_t)(g * 16 + sg_r) * 1024 + hw * 32 + sg_c, &Vs[0][hw * 2048 + g * 512]);
    }
    // stage bf16 mask row (waves 0,1; drained by the first loop-top barrier)
    if (wave < 2)
        GLDS(maskv + (size_t)b * 1024 + wave * 512 + lane * 8, maskl + wave * 512);

    const uint16_t* Qp = Qh + ((size_t)bh * 1024 + qb) * 64;
    short8 aq0 = *(const short8*)(Qp + (size_t)lrow * 64 + quad * 8);
    short8 aq1 = *(const short8*)(Qp + (size_t)lrow * 64 + 32 + quad * 8);

    const f32x4 fz = {0.f, 0.f, 0.f, 0.f};

    // ---- prologue: 16x272 pos-logit slab (pre-scaled by CS), B-frags from
    // global (L2-hot). cvt_pk packs pairs; each wave writes only its 16 rows.
#pragma unroll 4
    for (int nt = 0; nt < 17; ++nt) {
        short8 pb0 = *(const short8*)(pos + (size_t)(nt * 16 + lrow) * 64 + quad * 8);
        short8 pb1 = *(const short8*)(pos + (size_t)(nt * 16 + lrow) * 64 + 32 + quad * 8);
        f32x4 c = __builtin_amdgcn_mfma_f32_16x16x32_bf16(aq0, pb0, fz, 0, 0, 0);
        c = __builtin_amdgcn_mfma_f32_16x16x32_bf16(aq1, pb1, c, 0, 0, 0);
        const uint32_t p01 = cvt_pk_bf16(c[0] * CS, c[1] * CS);
        const uint32_t p23 = cvt_pk_bf16(c[2] * CS, c[3] * CS);
        const int row = wave * 16 + quad * 4;
        const int col = nt * 16 + lrow;
        Qpos_l[row + 0][col] = (uint16_t)p01;
        Qpos_l[row + 1][col] = (uint16_t)(p01 >> 16);
        Qpos_l[row + 2][col] = (uint16_t)p23;
        Qpos_l[row + 3][col] = (uint16_t)(p23 >> 16);
    }

    float pcl[4], pch[4];
#pragma unroll
    for (int r = 0; r < 4; ++r) {
        int ql = wave * 16 + quad * 4 + r;
        pcl[r] = bf2f(Qpos_l[ql][0]);      // already * CS
        pch[r] = bf2f(Qpos_l[ql][256]);
    }

    f32x4 o[4] = {fz, fz, fz, fz};
    f32x4 lacc = fz;   // denominator accumulator (every lane: full row sum)

    for (int kb = 0; kb < 1024; kb += 64) {
        const int cur = (kb >> 6) & 1;
        __syncthreads();  // drains prefetch (issued last iter); guards buffers
        if (kb + 64 < 1024) {
            const int nxt = cur ^ 1;
#pragma unroll
            for (int gg = 0; gg < 2; ++gg) {
                int g = gw + gg;
                GLDS(Kp + (size_t)(kb + 64 + g * 16 + sg_r) * 64 + hw * 32 + sg_c,
                     &Ks[nxt][hw * 2048 + g * 512]);
                GLDS(Vp + (size_t)(g * 16 + sg_r) * 1024 + kb + 64 + hw * 32 + sg_c,
                     &Vs[nxt][hw * 2048 + g * 512]);
            }
        }
        const uint16_t* Kc = Ks[cur];
        const uint16_t* Vc = Vs[cur];

        f32x4 s[4];
        __builtin_amdgcn_s_setprio(1);
#pragma unroll
        for (int j = 0; j < 4; ++j) {
            short8 k0 = *(const short8*)(Kc + (j * 16 + lrow) * 32 + rdc);
            short8 k1 = *(const short8*)(Kc + 2048 + (j * 16 + lrow) * 32 + rdc);
            s[j] = __builtin_amdgcn_mfma_f32_16x16x32_bf16(aq0, k0, fz, 0, 0, 0);
            s[j] = __builtin_amdgcn_mfma_f32_16x16x32_bf16(aq1, k1, s[j], 0, 0, 0);
        }
        __builtin_amdgcn_s_setprio(0);

        const int diff = kb - qb;                    // wave-uniform
        if (diff <= -192 || diff >= 144) {
            const bool low = (diff <= -192);
#pragma unroll
            for (int j = 0; j < 4; ++j) {
                float e[4];
#pragma unroll
                for (int r = 0; r < 4; ++r) {
                    float pc = low ? pcl[r] : pch[r];
                    e[r] = exp2_raw(__builtin_fmaf(s[j][r], CS, pc));
                }
                const uint32_t p01 = cvt_pk_bf16(e[0], e[1]);
                const uint32_t p23 = cvt_pk_bf16(e[2], e[3]);
                const int col = j * 16 + lrow;
                const int rw = quad * 4;
                Pl[wave][rw + 0][col] = (uint16_t)p01;
                Pl[wave][rw + 1][col] = (uint16_t)(p01 >> 16);
                Pl[wave][rw + 2][col] = (uint16_t)p23;
                Pl[wave][rw + 3][col] = (uint16_t)(p23 >> 16);
            }
        } else {
#pragma unroll
            for (int j = 0; j < 4; ++j) {
                const int key = kb + j * 16 + lrow;
                float e[4];
#pragma unroll
                for (int r = 0; r < 4; ++r) {
                    int q = qb + quad * 4 + r;
                    int ql = q & 63;
                    int rel = min(max(key - q, -128), 128) + 128;
                    float p = bf2f(Qpos_l[ql][rel]);   // already * CS
                    e[r] = exp2_raw(__builtin_fmaf(s[j][r], CS, p));
                }
                const uint32_t p01 = cvt_pk_bf16(e[0], e[1]);
                const uint32_t p23 = cvt_pk_bf16(e[2], e[3]);
                const int col = j * 16 + lrow;
                const int rw = quad * 4;
                Pl[wave][rw + 0][col] = (uint16_t)p01;
                Pl[wave][rw + 1][col] = (uint16_t)(p01 >> 16);
                Pl[wave][rw + 2][col] = (uint16_t)p23;
                Pl[wave][rw + 3][col] = (uint16_t)(p23 >> 16);
            }
        }
        short8 ap0 = *(const short8*)(&Pl[wave][lrow][quad * 8]);
        short8 ap1 = *(const short8*)(&Pl[wave][lrow][32 + quad * 8]);
        // mask B-frags: broadcast reads (same addr within each quad group)
        short8 bm0 = *(const short8*)(maskl + kb + quad * 8);
        short8 bm1 = *(const short8*)(maskl + kb + 32 + quad * 8);

        __builtin_amdgcn_s_setprio(1);
#pragma unroll
        for (int dt = 0; dt < 4; ++dt) {
            short8 v0 = *(const short8*)(Vc + (dt * 16 + lrow) * 32 + rdc);
            short8 v1 = *(const short8*)(Vc + 2048 + (dt * 16 + lrow) * 32 + rdc);
            o[dt] = __builtin_amdgcn_mfma_f32_16x16x32_bf16(ap0, v0, o[dt], 0, 0, 0);
            o[dt] = __builtin_amdgcn_mfma_f32_16x16x32_bf16(ap1, v1, o[dt], 0, 0, 0);
        }
        lacc = __builtin_amdgcn_mfma_f32_16x16x32_bf16(ap0, bm0, lacc, 0, 0, 0);
        lacc = __builtin_amdgcn_mfma_f32_16x16x32_bf16(ap1, bm1, lacc, 0, 0, 0);
        __builtin_amdgcn_s_setprio(0);
    }

    float inv[4];
#pragma unroll
    for (int r = 0; r < 4; ++r) inv[r] = 1.0f / lacc[r];

#pragma unroll
    for (int dt = 0; dt < 4; ++dt)
#pragma unroll
        for (int r = 0; r < 4; ++r) {
            size_t row = (size_t)b * 1024 + qb + quad * 4 + r;
            size_t col = (size_t)h * 64 + dt * 16 + lrow;
            comb[row * 1024 + col] = f2bf(o[dt][r] * inv[r]);
        }
}

// ---------------------------------------------------------------------------
// ws layout (~56.2 MB; ws_size >= ~72 MB evidenced rounds 0-3):
// Qh 8 | Khd 8 | Vt 8 | xqb 8 (comb reuse) | xkb 8 | xvb 8 | W*4 8 | posb |
// mbits | mvals
// ---------------------------------------------------------------------------
extern "C" void kernel_launch(void* const* d_in, const int* in_sizes, int n_in,
                              void* d_out, int out_size, void* d_ws, size_t ws_size,
                              hipStream_t stream)
{
    const float* x_q = (const float*)d_in[0];
    const float* x_k = (const float*)d_in[1];
    const float* x_v = (const float*)d_in[2];
    const void*  msk = d_in[3];
    const float* Wq  = (const float*)d_in[4];
    const float* Wk  = (const float*)d_in[5];
    const float* Wv  = (const float*)d_in[6];
    const float* Wo  = (const float*)d_in[7];
    const float* pos = (const float*)d_in[8];

    char* ws = (char*)d_ws;
    const size_t MB = 1u << 20;
    uint16_t* Qh   = (uint16_t*)(ws);
    uint16_t* Khd  = (uint16_t*)(ws + 8 * MB);
    uint16_t* Vt   = (uint16_t*)(ws + 16 * MB);
    uint16_t* xqb  = (uint16_t*)(ws + 24 * MB);
    uint16_t* xkb  = (uint16_t*)(ws + 32 * MB);
    uint16_t* xvb  = (uint16_t*)(ws + 40 * MB);
    uint16_t* Wqb  = (uint16_t*)(ws + 48 * MB);
    uint16_t* Wkb  = (uint16_t*)(ws + 50 * MB);
    uint16_t* Wvb  = (uint16_t*)(ws + 52 * MB);
    uint16_t* Wob  = (uint16_t*)(ws + 54 * MB);
    uint16_t* posb = (uint16_t*)(ws + 56 * MB);       // 272x64 bf16, rows 257+ zero
    unsigned long long* mbits = (unsigned long long*)(ws + 56 * MB + 65536);
    uint16_t* mvals = (uint16_t*)(ws + 56 * MB + 65536 + 4096);  // 4x1024 bf16
    uint16_t* comb = xqb;  // xqb dead after projections; flash runs after them

    CvtArgs ca{};
    int ns = 0;
    ca.seg[ns++] = {x_q, xqb, 524288};
    ca.seg[ns++] = {x_k, xkb, 524288};
    ca.seg[ns++] = {x_v, xvb, 524288};
    ca.seg[ns++] = {Wq, Wqb, 131072};
    ca.seg[ns++] = {Wk, Wkb, 131072};
    ca.seg[ns++] = {Wv, Wvb, 131072};
    ca.seg[ns++] = {Wo, Wob, 131072};
    ca.seg[ns++] = {pos, posb, 2056};              // 257*64/8
    ca.seg[ns++] = {nullptr, posb + 16448, 120};   // zero rows 257..271
    ca.nseg = ns;
    ca.mraw = msk;
    ca.mbits = mbits;
    ca.mvals = mvals;
    cvt_bf16<<<dim3(512), dim3(256), 0, stream>>>(ca);

    // Fused Q/K/V projections, BK=64 two-half staging: 32x8x3 = 768 blocks
    gemm128_qkv<<<dim3(32, 8, 3), dim3(256), 0, stream>>>(
        xqb, xkb, xvb, Wqb, Wkb, Wvb, Qh, Khd, Vt, mbits);

    flash_attn<<<dim3(1024), dim3(256), 0, stream>>>(Qh, Khd, Vt, posb, mvals, comb);

    // Output projection: comb(bf16) @ Wo_b^T -> fp32 d_out (64x128, BK=64)
    gemm_out<<<dim3(64, 8), dim3(256), 0, stream>>>(
        comb, Wob, (float*)d_out, 4096, 1024, 1024);
}

// Round 5
// 229.210 us; speedup vs baseline: 1.3179x; 1.0352x over previous
//
#include <hip/hip_runtime.h>
#include <hip/hip_bf16.h>
#include <stdint.h>

typedef __attribute__((ext_vector_type(8))) short short8;  // 8 bf16 (4 VGPRs)
typedef __attribute__((ext_vector_type(4))) float f32x4;   // 4 fp32 acc

__device__ __forceinline__ uint16_t f2bf(float f) {
    union { float f; uint32_t u; } v; v.f = f;
    uint32_t r = v.u + 0x7FFF + ((v.u >> 16) & 1);  // RNE
    return (uint16_t)(r >> 16);
}
__device__ __forceinline__ float bf2f(uint16_t u) {
    union { uint32_t u; float f; } v; v.u = ((uint32_t)u) << 16;
    return v.f;
}
__device__ __forceinline__ float exp2_raw(float x) {
    float r;
    asm("v_exp_f32 %0, %1" : "=v"(r) : "v"(x));
    return r;
}
__device__ __forceinline__ uint32_t cvt_pk_bf16(float lo, float hi) {
    uint32_t r;
    asm("v_cvt_pk_bf16_f32 %0, %1, %2" : "=v"(r) : "v"(lo), "v"(hi));
    return r;
}

template<int F32>
__device__ __forceinline__ uint4 load8(const void* p, size_t off) {
    if (F32) {
        const float* f = (const float*)p + off;
        float4 f0 = *(const float4*)f;
        float4 f1 = *(const float4*)(f + 4);
        uint4 r;
        r.x = (uint32_t)f2bf(f0.x) | ((uint32_t)f2bf(f0.y) << 16);
        r.y = (uint32_t)f2bf(f0.z) | ((uint32_t)f2bf(f0.w) << 16);
        r.z = (uint32_t)f2bf(f1.x) | ((uint32_t)f2bf(f1.y) << 16);
        r.w = (uint32_t)f2bf(f1.z) | ((uint32_t)f2bf(f1.w) << 16);
        return r;
    } else {
        return *(const uint4*)((const uint16_t*)p + off);
    }
}

// global -> LDS direct DMA, 16 B/lane; LDS dest = wave-uniform base + lane*16.
#define GLDS(gp, lp) __builtin_amdgcn_global_load_lds( \
    (const __attribute__((address_space(1))) void*)(gp), \
    (__attribute__((address_space(3))) void*)(lp), 16, 0, 0)

// ---------------------------------------------------------------------------
// cvt (x + weights + pos) + mask canonicalization fused. Mask products:
//  * mbits: 1024-bit-per-batch bitmask (used by gemm128_qkv V-epilogue)
//  * mvals: bf16 {1.0 unmasked, 0.0 masked} per (b,k) — flash_attn's
//    denominator B-fragment (lsum via MFMA instead of 64 VALU adds/iter).
// ---------------------------------------------------------------------------
struct CvtSeg { const float* s; uint16_t* d; int n8; };
struct CvtArgs {
    CvtSeg seg[9]; int nseg;
    const void* mraw; unsigned long long* mbits; uint16_t* mvals;
};

__global__ __launch_bounds__(256) void cvt_bf16(CvtArgs a)
{
    if (blockIdx.x == 0) {
        __shared__ int flags[3];
        __shared__ uint8_t mloc[4096];
        const uint32_t* w = (const uint32_t*)a.mraw;
        const uint8_t* b8 = (const uint8_t*)a.mraw;
        const int t = threadIdx.x;
        if (t < 3) flags[t] = 0;
        __syncthreads();
        int fbyte = 0, ff32 = 0, fodd = 0;
        for (int i = t; i < 1024; i += 256) {
            uint32_t v = w[i];
            if (v != 0u && v != 1u && v != 0x3F800000u) fbyte = 1;
            if (v == 0x3F800000u) ff32 = 1;
            if ((i & 1) && v != 0u) fodd = 1;
        }
        if (fbyte) atomicOr(&flags[0], 1);
        if (ff32)  atomicOr(&flags[1], 1);
        if (fodd)  atomicOr(&flags[2], 1);
        __syncthreads();
        int mode;  // 0 = word, 1 = byte, 2 = int64
        if (flags[0]) mode = 1;
        else if (flags[1]) mode = 0;
        else if (!flags[2]) mode = 2;
        else mode = 0;
        for (int k = t; k < 4096; k += 256) {
            int val;
            if (mode == 1)      val = (b8[k] != 0);
            else if (mode == 2) val = (w[2 * k] != 0u);
            else                val = (w[k] != 0u);
            mloc[k] = (uint8_t)val;
        }
        __syncthreads();
        for (int k = t; k < 4096; k += 256)
            a.mvals[k] = mloc[k] ? (uint16_t)0 : (uint16_t)0x3F80;
        if (t < 64) {
            uint64_t bits = 0;
#pragma unroll
            for (int i = 0; i < 64; ++i)
                bits |= (uint64_t)mloc[t * 64 + i] << i;
            a.mbits[t] = bits;
        }
    }
    const int tid = blockIdx.x * 256 + threadIdx.x;
    const int stride = gridDim.x * 256;
    for (int s = 0; s < a.nseg; ++s) {
        const float* src = a.seg[s].s;
        uint16_t* dst = a.seg[s].d;
        const int n8 = a.seg[s].n8;
        if (src) {
            for (int i = tid; i < n8; i += stride)
                *(uint4*)(dst + (size_t)i * 8) = load8<1>(src, (size_t)i * 8);
        } else {
            const uint4 z = {0u, 0u, 0u, 0u};
            for (int i = tid; i < n8; i += stride)
                *(uint4*)(dst + (size_t)i * 8) = z;
        }
    }
}

// ---------------------------------------------------------------------------
// QKV GEMM, 128x128 tile, BK=64 as TWO 128x32 sub-tiles per operand — exact
// r13 version (best measured). Pure-bf16 glds staging, 32 MFMA per barrier
// pair. NOTE (r9/r10/r14 lesson): never reduce MFMA-per-barrier; never stage
// fp32 rows into LDS (16-way conflict) or via in-loop vector loads (exposed
// vmcnt drain).
// r4 LESSON: the V-mask epilogue must NOT vector-load mbits per (i,j) — that
// made 16 stores load-dependent and cost ~9.6us. The word is wave-uniform
// (tl spans <64 bits): ONE readfirstlane'd s_load before the loops.
// ---------------------------------------------------------------------------
__global__ __launch_bounds__(256) void gemm128_qkv(
    const uint16_t* __restrict__ xq, const uint16_t* __restrict__ xk, const uint16_t* __restrict__ xv,
    const uint16_t* __restrict__ Wq, const uint16_t* __restrict__ Wk, const uint16_t* __restrict__ Wv,
    uint16_t* __restrict__ Qh, uint16_t* __restrict__ Khd, uint16_t* __restrict__ Vt,
    const unsigned long long* __restrict__ mbits)
{
    __shared__ alignas(16) uint16_t As[2][128 * 32];   // k-halves
    __shared__ alignas(16) uint16_t Bs[2][128 * 32];

    const int z = blockIdx.z;
    const uint16_t* A = (z == 0) ? xq : (z == 1) ? xk : xv;
    const uint16_t* B = (z == 0) ? Wq : (z == 1) ? Wk : Wv;
    uint16_t* C = (z == 0) ? Qh : (z == 1) ? Khd : Vt;
    const int cm = (z == 2) ? 2 : 1;
    const int bm = blockIdx.x, bn = blockIdx.y;
    const int K = 1024;

    const int t = threadIdx.x;
    const int lane = t & 63, wave = t >> 6;
    const int lrow = lane & 15, quad = lane >> 4;
    const int wr = (wave >> 1) * 64, wc = (wave & 1) * 64;
    const int g_row = wave * 16 + (lane >> 2);
    const int g_col = (lane & 3) * 8;

    const f32x4 fz = {0.f, 0.f, 0.f, 0.f};
    f32x4 acc[4][4];
#pragma unroll
    for (int i = 0; i < 4; ++i)
#pragma unroll
        for (int j = 0; j < 4; ++j) acc[i][j] = fz;

    for (int k0 = 0; k0 < K; k0 += 64) {
        __syncthreads();
#pragma unroll
        for (int kh = 0; kh < 2; ++kh) {
            const int kk = k0 + kh * 32;
            GLDS(A + (size_t)(bm * 128 + g_row) * K + kk + g_col,      As[kh] + wave * 512);
            GLDS(A + (size_t)(bm * 128 + g_row + 64) * K + kk + g_col, As[kh] + wave * 512 + 2048);
            GLDS(B + (size_t)(bn * 128 + g_row) * K + kk + g_col,      Bs[kh] + wave * 512);
            GLDS(B + (size_t)(bn * 128 + g_row + 64) * K + kk + g_col, Bs[kh] + wave * 512 + 2048);
        }
        __syncthreads();

#pragma unroll
        for (int kh = 0; kh < 2; ++kh) {
            short8 a[4], b[4];
#pragma unroll
            for (int i = 0; i < 4; ++i)
                a[i] = *(const short8*)(As[kh] + (wr + i * 16 + lrow) * 32 + quad * 8);
#pragma unroll
            for (int j = 0; j < 4; ++j)
                b[j] = *(const short8*)(Bs[kh] + (wc + j * 16 + lrow) * 32 + quad * 8);
#pragma unroll
            for (int i = 0; i < 4; ++i)
#pragma unroll
                for (int j = 0; j < 4; ++j)
                    acc[i][j] = __builtin_amdgcn_mfma_f32_16x16x32_bf16(a[i], b[j], acc[i][j], 0, 0, 0);
        }
    }

    if (cm == 2) {
        __syncthreads();
        uint16_t* scr = As[0] + wave * 1024;
        // wave-uniform mask word: mg0 is 64-aligned and i*16+m8 < 64, so all
        // (i,j) stores of this wave hit ONE u64. s_load once, VALU-extract.
        const int mg0 = bm * 128 + wr;
        const int widx = __builtin_amdgcn_readfirstlane((mg0 >> 10) * 16 + ((mg0 & 1023) >> 6));
        const uint64_t mword = mbits[widx];
        const uint64_t mw64 = mword >> ((lane & 1) * 8);
#pragma unroll
        for (int i = 0; i < 4; ++i)
#pragma unroll
            for (int j = 0; j < 4; ++j) {
                uint2 pk;
                pk.x = (uint32_t)f2bf(acc[i][j][0]) | ((uint32_t)f2bf(acc[i][j][1]) << 16);
                pk.y = (uint32_t)f2bf(acc[i][j][2]) | ((uint32_t)f2bf(acc[i][j][3]) << 16);
                *(uint2*)(scr + lrow * 16 + quad * 4) = pk;
                if (lane < 32) {
                    int n = lane >> 1, m8 = (lane & 1) * 8;
                    short8 vv = *(const short8*)(scr + n * 16 + m8);
                    int ng = bn * 128 + wc + j * 16 + n;        // (h,d)
                    int hh = ng >> 6, d = ng & 63;
                    int mg = bm * 128 + wr + i * 16;            // t base
                    int bb = mg >> 10, tl = (mg & 1023) + m8;
                    uint32_t eb = (uint32_t)(mw64 >> (i * 16)) & 0xFFu;
                    if (eb) {
                        union { short8 s; uint32_t u[4]; } uw;
                        uw.s = vv;
#pragma unroll
                        for (int c = 0; c < 4; ++c) {
                            uint32_t km = (((eb >> (2 * c)) & 1) ? 0u : 0x0000FFFFu)
                                        | (((eb >> (2 * c + 1)) & 1) ? 0u : 0xFFFF0000u);
                            uw.u[c] &= km;
                        }
                        vv = uw.s;
                    }
                    *(short8*)(C + ((((size_t)bb * 16 + hh) * 64 + d) * 1024 + tl)) = vv;
                }
            }
        return;
    }

#pragma unroll
    for (int i = 0; i < 4; ++i)
#pragma unroll
        for (int j = 0; j < 4; ++j)
#pragma unroll
            for (int r = 0; r < 4; ++r) {
                // verified C/D map: row = quad*4 + reg, col = lane&15
                int m = bm * 128 + wr + i * 16 + quad * 4 + r;
                int n = bn * 128 + wc + j * 16 + lrow;
                int bb = m >> 10, tt = m & 1023, hh = n >> 6, d = n & 63;
                C[(((size_t)bb * 16 + hh) * 1024 + tt) * 64 + d] = f2bf(acc[i][j][r]);
            }
}

// ---------------------------------------------------------------------------
// Output projection, 64x128 tiles (512 blocks = 2/CU), BK=64 — exact r13
// version. 16 MFMA/iter. LDS 24KB.
// ---------------------------------------------------------------------------
__global__ __launch_bounds__(256) void gemm_out(
    const uint16_t* __restrict__ A, const uint16_t* __restrict__ B,
    float* __restrict__ C, int M, int N, int K)
{
    __shared__ alignas(16) uint16_t As[2][64 * 32];
    __shared__ alignas(16) uint16_t Bs[2][128 * 32];

    const int t = threadIdx.x;
    const int lane = t & 63, wave = t >> 6;
    const int lrow = lane & 15, quad = lane >> 4;
    const int wr = (wave >> 1) * 32, wc = (wave & 1) * 64;
    const int g_row = wave * 16 + (lane >> 2);
    const int g_col = (lane & 3) * 8;
    const int bm = blockIdx.x, bn = blockIdx.y;

    const f32x4 fz = {0.f, 0.f, 0.f, 0.f};
    f32x4 acc[2][4];
#pragma unroll
    for (int i = 0; i < 2; ++i)
#pragma unroll
        for (int j = 0; j < 4; ++j) acc[i][j] = fz;

    for (int k0 = 0; k0 < K; k0 += 64) {
        __syncthreads();
#pragma unroll
        for (int kh = 0; kh < 2; ++kh) {
            const int kk = k0 + kh * 32;
            GLDS(A + (size_t)(bm * 64 + g_row) * K + kk + g_col,       As[kh] + wave * 512);
            GLDS(B + (size_t)(bn * 128 + g_row) * K + kk + g_col,      Bs[kh] + wave * 512);
            GLDS(B + (size_t)(bn * 128 + g_row + 64) * K + kk + g_col, Bs[kh] + wave * 512 + 2048);
        }
        __syncthreads();

#pragma unroll
        for (int kh = 0; kh < 2; ++kh) {
            short8 a[2], b[4];
#pragma unroll
            for (int i = 0; i < 2; ++i)
                a[i] = *(const short8*)(As[kh] + (wr + i * 16 + lrow) * 32 + quad * 8);
#pragma unroll
            for (int j = 0; j < 4; ++j)
                b[j] = *(const short8*)(Bs[kh] + (wc + j * 16 + lrow) * 32 + quad * 8);
#pragma unroll
            for (int i = 0; i < 2; ++i)
#pragma unroll
                for (int j = 0; j < 4; ++j)
                    acc[i][j] = __builtin_amdgcn_mfma_f32_16x16x32_bf16(a[i], b[j], acc[i][j], 0, 0, 0);
        }
    }

#pragma unroll
    for (int i = 0; i < 2; ++i)
#pragma unroll
        for (int j = 0; j < 4; ++j)
#pragma unroll
            for (int r = 0; r < 4; ++r) {
                int m = bm * 64 + wr + i * 16 + quad * 4 + r;
                int n = bn * 128 + wc + j * 16 + lrow;
                C[(size_t)m * N + n] = acc[i][j][r];
            }
}

// ---------------------------------------------------------------------------
// Flash attention v12 — v11 + T15 pipeline: PV runs ONE TILE BEHIND, with
// P-frags (ap) and V-frags (vv, 32 VGPR) carried in registers across the
// iteration. Loop body: barrier -> GLDS(t+1) -> [PV(t-1) 10 reg-MFMAs +
// QK(t) 8 MFMAs] as one setprio cluster -> SM(t) overlapping matrix drain
// -> reload ap/vv. Register-carried V is also REQUIRED: GLDS(t+1)
// overwrites V(t-1)'s buffer (reads complete at the barrier's lgkm drain,
// DMA lands after). VGPR is free (LDS-bound occupancy).
// Kept: mask-free softmax (V pre-zeroed), MFMA denominator (lacc), exp2+CS,
// cvt_pk, Qpos 277, K/V chunk swizzle.
// LDS: Ks 16K + Vs 16K + Qpos_l 35.5K + Pl 9K + maskl 2K -> 79.9KB, 2/CU.
// ---------------------------------------------------------------------------
#define FA_QK(KC_)                                                              \
{                                                                               \
    _Pragma("unroll")                                                           \
    for (int j = 0; j < 4; ++j) {                                               \
        short8 k0 = *(const short8*)((KC_) + (j * 16 + lrow) * 32 + rdc);       \
        short8 k1 = *(const short8*)((KC_) + 2048 + (j * 16 + lrow) * 32 + rdc);\
        s[j] = __builtin_amdgcn_mfma_f32_16x16x32_bf16(aq0, k0, fz, 0, 0, 0);   \
        s[j] = __builtin_amdgcn_mfma_f32_16x16x32_bf16(aq1, k1, s[j], 0, 0, 0); \
    }                                                                           \
}

#define FA_PV(KBM_)                                                             \
{                                                                               \
    short8 bm0 = *(const short8*)(maskl + (KBM_) + quad * 8);                   \
    short8 bm1 = *(const short8*)(maskl + (KBM_) + 32 + quad * 8);              \
    _Pragma("unroll")                                                           \
    for (int dt = 0; dt < 4; ++dt) {                                            \
        o[dt] = __builtin_amdgcn_mfma_f32_16x16x32_bf16(ap0, vv[dt * 2 + 0], o[dt], 0, 0, 0); \
        o[dt] = __builtin_amdgcn_mfma_f32_16x16x32_bf16(ap1, vv[dt * 2 + 1], o[dt], 0, 0, 0); \
    }                                                                           \
    lacc = __builtin_amdgcn_mfma_f32_16x16x32_bf16(ap0, bm0, lacc, 0, 0, 0);    \
    lacc = __builtin_amdgcn_mfma_f32_16x16x32_bf16(ap1, bm1, lacc, 0, 0, 0);    \
}

#define FA_SM(KB_)                                                              \
{                                                                               \
    const int diff = (KB_) - qb;                                                \
    if (diff <= -192 || diff >= 144) {                                          \
        const bool low = (diff <= -192);                                        \
        _Pragma("unroll")                                                       \
        for (int j = 0; j < 4; ++j) {                                           \
            float e[4];                                                         \
            _Pragma("unroll")                                                   \
            for (int r = 0; r < 4; ++r) {                                       \
                float pc = low ? pcl[r] : pch[r];                               \
                e[r] = exp2_raw(__builtin_fmaf(s[j][r], CS, pc));               \
            }                                                                   \
            const uint32_t p01 = cvt_pk_bf16(e[0], e[1]);                       \
            const uint32_t p23 = cvt_pk_bf16(e[2], e[3]);                       \
            const int col = j * 16 + lrow;                                      \
            const int rw = quad * 4;                                            \
            Pl[wave][rw + 0][col] = (uint16_t)p01;                              \
            Pl[wave][rw + 1][col] = (uint16_t)(p01 >> 16);                      \
            Pl[wave][rw + 2][col] = (uint16_t)p23;                              \
            Pl[wave][rw + 3][col] = (uint16_t)(p23 >> 16);                      \
        }                                                                       \
    } else {                                                                    \
        _Pragma("unroll")                                                       \
        for (int j = 0; j < 4; ++j) {                                           \
            const int key = (KB_) + j * 16 + lrow;                              \
            float e[4];                                                         \
            _Pragma("unroll")                                                   \
            for (int r = 0; r < 4; ++r) {                                       \
                int q = qb + quad * 4 + r;                                      \
                int ql = q & 63;                                                \
                int rel = min(max(key - q, -128), 128) + 128;                   \
                float p = bf2f(Qpos_l[ql][rel]);                                \
                e[r] = exp2_raw(__builtin_fmaf(s[j][r], CS, p));                \
            }                                                                   \
            const uint32_t p01 = cvt_pk_bf16(e[0], e[1]);                       \
            const uint32_t p23 = cvt_pk_bf16(e[2], e[3]);                       \
            const int col = j * 16 + lrow;                                      \
            const int rw = quad * 4;                                            \
            Pl[wave][rw + 0][col] = (uint16_t)p01;                              \
            Pl[wave][rw + 1][col] = (uint16_t)(p01 >> 16);                      \
            Pl[wave][rw + 2][col] = (uint16_t)p23;                              \
            Pl[wave][rw + 3][col] = (uint16_t)(p23 >> 16);                      \
        }                                                                       \
    }                                                                           \
    ap0 = *(const short8*)(&Pl[wave][lrow][quad * 8]);                          \
    ap1 = *(const short8*)(&Pl[wave][lrow][32 + quad * 8]);                     \
}

#define FA_VV(VC_)                                                              \
{                                                                               \
    _Pragma("unroll")                                                           \
    for (int dt = 0; dt < 4; ++dt) {                                            \
        vv[dt * 2 + 0] = *(const short8*)((VC_) + (dt * 16 + lrow) * 32 + rdc); \
        vv[dt * 2 + 1] = *(const short8*)((VC_) + 2048 + (dt * 16 + lrow) * 32 + rdc); \
    }                                                                           \
}

__global__ __launch_bounds__(256) void flash_attn(
    const uint16_t* __restrict__ Qh, const uint16_t* __restrict__ Kh,
    const uint16_t* __restrict__ Vt, const uint16_t* __restrict__ pos,
    const uint16_t* __restrict__ maskv, uint16_t* __restrict__ comb)
{
    const int blk = blockIdx.x;     // 0..1023
    const int jj = blk >> 3;        // 0..127
    const int bh = (blk & 7) * 8 + (jj >> 4);   // XCD-locality swizzle
    const int qt = jj & 15;
    const int b = bh >> 4;
    const int h = bh & 15;
    const int t = threadIdx.x;
    const int lane = t & 63;
    const int wave = t >> 6;
    const int lrow = lane & 15;
    const int quad = lane >> 4;
    const int qb = qt * 64 + wave * 16;

    __shared__ alignas(16) uint16_t Ks[2][4096];       // 2 x 8 KB
    __shared__ alignas(16) uint16_t Vs[2][4096];       // 2 x 8 KB
    __shared__ alignas(16) uint16_t Qpos_l[64][277];   // 35456 B, W=277: bank-clean
    __shared__ alignas(16) uint16_t Pl[4][16][72];     // 9216 B
    __shared__ alignas(16) uint16_t maskl[1024];       // 2 KB bf16 0/1 per key

    const uint16_t* Kp = Kh + (size_t)bh * 65536;
    const uint16_t* Vp = Vt + (size_t)bh * 65536;

    const int sg_r = lane >> 2;
    // pre-swizzled global source chunk: LDS stays linear for GLDS, data lands
    // at chunk position c with content c^((row>>1)&3). Read side mirrors it.
    const int sg_c = ((lane & 3) ^ ((sg_r >> 1) & 3)) * 8;
    const int hw = wave >> 1;
    const int gw = (wave & 1) * 2;
    const int rdc = (quad ^ ((lrow >> 1) & 3)) * 8;    // swizzled read chunk

    const float CS = 0.18033688011f;   // 0.125 * log2(e)

    // issue tile-0 staging first: latency hides under the pos-slab prologue
#pragma unroll
    for (int gg = 0; gg < 2; ++gg) {
        int g = gw + gg;
        GLDS(Kp + (size_t)(g * 16 + sg_r) * 64 + hw * 32 + sg_c, &Ks[0][hw * 2048 + g * 512]);
        GLDS(Vp + (size_t)(g * 16 + sg_r) * 1024 + hw * 32 + sg_c, &Vs[0][hw * 2048 + g * 512]);
    }
    // stage bf16 mask row (waves 0,1; drained by the first barrier)
    if (wave < 2)
        GLDS(maskv + (size_t)b * 1024 + wave * 512 + lane * 8, maskl + wave * 512);

    const uint16_t* Qp = Qh + ((size_t)bh * 1024 + qb) * 64;
    short8 aq0 = *(const short8*)(Qp + (size_t)lrow * 64 + quad * 8);
    short8 aq1 = *(const short8*)(Qp + (size_t)lrow * 64 + 32 + quad * 8);

    const f32x4 fz = {0.f, 0.f, 0.f, 0.f};

    // ---- prologue: 16x272 pos-logit slab (pre-scaled by CS), B-frags from
    // global (L2-hot). cvt_pk packs pairs; each wave writes only its 16 rows.
#pragma unroll 4
    for (int nt = 0; nt < 17; ++nt) {
        short8 pb0 = *(const short8*)(pos + (size_t)(nt * 16 + lrow) * 64 + quad * 8);
        short8 pb1 = *(const short8*)(pos + (size_t)(nt * 16 + lrow) * 64 + 32 + quad * 8);
        f32x4 c = __builtin_amdgcn_mfma_f32_16x16x32_bf16(aq0, pb0, fz, 0, 0, 0);
        c = __builtin_amdgcn_mfma_f32_16x16x32_bf16(aq1, pb1, c, 0, 0, 0);
        const uint32_t p01 = cvt_pk_bf16(c[0] * CS, c[1] * CS);
        const uint32_t p23 = cvt_pk_bf16(c[2] * CS, c[3] * CS);
        const int row = wave * 16 + quad * 4;
        const int col = nt * 16 + lrow;
        Qpos_l[row + 0][col] = (uint16_t)p01;
        Qpos_l[row + 1][col] = (uint16_t)(p01 >> 16);
        Qpos_l[row + 2][col] = (uint16_t)p23;
        Qpos_l[row + 3][col] = (uint16_t)(p23 >> 16);
    }

    float pcl[4], pch[4];
#pragma unroll
    for (int r = 0; r < 4; ++r) {
        int ql = wave * 16 + quad * 4 + r;
        pcl[r] = bf2f(Qpos_l[ql][0]);      // already * CS
        pch[r] = bf2f(Qpos_l[ql][256]);
    }

    f32x4 o[4] = {fz, fz, fz, fz};
    f32x4 lacc = fz;   // denominator accumulator (every lane: full row sum)
    f32x4 s[4];
    short8 ap0, ap1, vv[8];

    // ---- tile 0: fill the pipeline ----
    __syncthreads();   // tile-0 K/V + maskl ready
#pragma unroll
    for (int gg = 0; gg < 2; ++gg) {
        int g = gw + gg;
        GLDS(Kp + (size_t)(64 + g * 16 + sg_r) * 64 + hw * 32 + sg_c, &Ks[1][hw * 2048 + g * 512]);
        GLDS(Vp + (size_t)(g * 16 + sg_r) * 1024 + 64 + hw * 32 + sg_c, &Vs[1][hw * 2048 + g * 512]);
    }
    __builtin_amdgcn_s_setprio(1);
    FA_QK(Ks[0])
    __builtin_amdgcn_s_setprio(0);
    FA_SM(0)
    FA_VV(Vs[0])

    // ---- main loop: PV one tile behind ----
    for (int ti = 1; ti < 16; ++ti) {
        const int kb = ti * 64;
        const uint16_t* Kc = Ks[ti & 1];
        const uint16_t* Vc = Vs[ti & 1];
        __syncthreads();   // K/V(ti) ready; prior ds_reads drained
        if (ti < 15) {
            const int nxt = (ti + 1) & 1;
#pragma unroll
            for (int gg = 0; gg < 2; ++gg) {
                int g = gw + gg;
                GLDS(Kp + (size_t)(kb + 64 + g * 16 + sg_r) * 64 + hw * 32 + sg_c,
                     &Ks[nxt][hw * 2048 + g * 512]);
                GLDS(Vp + (size_t)(g * 16 + sg_r) * 1024 + kb + 64 + hw * 32 + sg_c,
                     &Vs[nxt][hw * 2048 + g * 512]);
            }
        }
        __builtin_amdgcn_s_setprio(1);
        FA_PV(kb - 64)     // reg-only MFMAs: fill matrix pipe immediately
        FA_QK(Kc)          // ds_read K + MFMAs
        __builtin_amdgcn_s_setprio(0);
        FA_SM(kb)          // VALU/trans overlaps matrix drain
        FA_VV(Vc)
    }
    // ---- drain: PV(15) ----
    __builtin_amdgcn_s_setprio(1);
    FA_PV(960)
    __builtin_amdgcn_s_setprio(0);

    float inv[4];
#pragma unroll
    for (int r = 0; r < 4; ++r) inv[r] = 1.0f / lacc[r];

#pragma unroll
    for (int dt = 0; dt < 4; ++dt)
#pragma unroll
        for (int r = 0; r < 4; ++r) {
            size_t row = (size_t)b * 1024 + qb + quad * 4 + r;
            size_t col = (size_t)h * 64 + dt * 16 + lrow;
            comb[row * 1024 + col] = f2bf(o[dt][r] * inv[r]);
        }
}

// ---------------------------------------------------------------------------
// ws layout (~56.2 MB; ws_size >= ~72 MB evidenced rounds 0-3):
// Qh 8 | Khd 8 | Vt 8 | xqb 8 (comb reuse) | xkb 8 | xvb 8 | W*4 8 | posb |
// mbits | mvals
// ---------------------------------------------------------------------------
extern "C" void kernel_launch(void* const* d_in, const int* in_sizes, int n_in,
                              void* d_out, int out_size, void* d_ws, size_t ws_size,
                              hipStream_t stream)
{
    const float* x_q = (const float*)d_in[0];
    const float* x_k = (const float*)d_in[1];
    const float* x_v = (const float*)d_in[2];
    const void*  msk = d_in[3];
    const float* Wq  = (const float*)d_in[4];
    const float* Wk  = (const float*)d_in[5];
    const float* Wv  = (const float*)d_in[6];
    const float* Wo  = (const float*)d_in[7];
    const float* pos = (const float*)d_in[8];

    char* ws = (char*)d_ws;
    const size_t MB = 1u << 20;
    uint16_t* Qh   = (uint16_t*)(ws);
    uint16_t* Khd  = (uint16_t*)(ws + 8 * MB);
    uint16_t* Vt   = (uint16_t*)(ws + 16 * MB);
    uint16_t* xqb  = (uint16_t*)(ws + 24 * MB);
    uint16_t* xkb  = (uint16_t*)(ws + 32 * MB);
    uint16_t* xvb  = (uint16_t*)(ws + 40 * MB);
    uint16_t* Wqb  = (uint16_t*)(ws + 48 * MB);
    uint16_t* Wkb  = (uint16_t*)(ws + 50 * MB);
    uint16_t* Wvb  = (uint16_t*)(ws + 52 * MB);
    uint16_t* Wob  = (uint16_t*)(ws + 54 * MB);
    uint16_t* posb = (uint16_t*)(ws + 56 * MB);       // 272x64 bf16, rows 257+ zero
    unsigned long long* mbits = (unsigned long long*)(ws + 56 * MB + 65536);
    uint16_t* mvals = (uint16_t*)(ws + 56 * MB + 65536 + 4096);  // 4x1024 bf16
    uint16_t* comb = xqb;  // xqb dead after projections; flash runs after them

    CvtArgs ca{};
    int ns = 0;
    ca.seg[ns++] = {x_q, xqb, 524288};
    ca.seg[ns++] = {x_k, xkb, 524288};
    ca.seg[ns++] = {x_v, xvb, 524288};
    ca.seg[ns++] = {Wq, Wqb, 131072};
    ca.seg[ns++] = {Wk, Wkb, 131072};
    ca.seg[ns++] = {Wv, Wvb, 131072};
    ca.seg[ns++] = {Wo, Wob, 131072};
    ca.seg[ns++] = {pos, posb, 2056};              // 257*64/8
    ca.seg[ns++] = {nullptr, posb + 16448, 120};   // zero rows 257..271
    ca.nseg = ns;
    ca.mraw = msk;
    ca.mbits = mbits;
    ca.mvals = mvals;
    cvt_bf16<<<dim3(512), dim3(256), 0, stream>>>(ca);

    // Fused Q/K/V projections, BK=64 two-half staging: 32x8x3 = 768 blocks
    gemm128_qkv<<<dim3(32, 8, 3), dim3(256), 0, stream>>>(
        xqb, xkb, xvb, Wqb, Wkb, Wvb, Qh, Khd, Vt, mbits);

    flash_attn<<<dim3(1024), dim3(256), 0, stream>>>(Qh, Khd, Vt, posb, mvals, comb);

    // Output projection: comb(bf16) @ Wo_b^T -> fp32 d_out (64x128, BK=64)
    gemm_out<<<dim3(64, 8), dim3(256), 0, stream>>>(
        comb, Wob, (float*)d_out, 4096, 1024, 1024);
}